// Round 11
// baseline (181.507 us; speedup 1.0000x reference)
//
#include <hip/hip_runtime.h>

typedef unsigned short u16;
typedef __attribute__((ext_vector_type(8))) __bf16 bf16x8;
typedef __attribute__((ext_vector_type(4))) float f32x4;

#define NB 2
#define NT 2048
#define ND 1024
#define NH 16
#define HD 64

__device__ __forceinline__ float b2f(u16 u) {
  union { float f; unsigned int i; } v; v.i = ((unsigned int)u) << 16; return v.f;
}
__device__ __forceinline__ u16 f2b(float f) {
  union { float f; unsigned int i; } v; v.f = f;
  unsigned int r = (v.i + 0x7FFFu + ((v.i >> 16) & 1u)) >> 16;
  return (u16)r;
}
// 2x f32 -> packed bf16 (RNE, same as f2b) in ONE VALU op. [T12 primitive]
__device__ __forceinline__ unsigned int cvtpk(float lo, float hi) {
  unsigned int pk;
  asm("v_cvt_pk_bf16_f32 %0, %1, %2" : "=v"(pk) : "v"(lo), "v"(hi));
  return pk;
}

__device__ __forceinline__ void gload_lds16(const u16* g, u16* lds) {
  __builtin_amdgcn_global_load_lds(
      (const __attribute__((address_space(1))) unsigned int*)(g),
      (__attribute__((address_space(3))) unsigned int*)(lds),
      16, 0, 0);
}

__device__ __forceinline__ f32x4 mfma16(bf16x8 a, bf16x8 b, f32x4 c) {
  return __builtin_amdgcn_mfma_f32_16x16x32_bf16(a, b, c, 0, 0, 0);
}

// DPP row_ror<N>: 16-lane-domain reduction at VALU latency (no ds_swizzle).
template <int N>
__device__ __forceinline__ float ror16(float x) {
  return __int_as_float(__builtin_amdgcn_update_dpp(
      __float_as_int(x), __float_as_int(x), 0x120 | N, 0xF, 0xF, true));
}
__device__ __forceinline__ float rsum16(float x) {
  x += ror16<8>(x);
  x += ror16<4>(x);
  x += ror16<2>(x);
  x += ror16<1>(x);
  return x;
}

// Fast sin/cos: radians -> revolutions, fract range-reduce, v_sin/v_cos.
__device__ __forceinline__ float fast_sin(float a) {
  float r = a * 0.15915494309189535f;
  r -= floorf(r);
  return __builtin_amdgcn_sinf(r);
}
__device__ __forceinline__ float fast_cos(float a) {
  float r = a * 0.15915494309189535f;
  r -= floorf(r);
  return __builtin_amdgcn_cosf(r);
}

// ---- merged input prep: cast + weight transposes + RoPE sin/cos table ------
// blocks [0,2048): cast; [2048,5120): qkv_w transpose; [5120,6144): out_w;
// [6144,6176): rope table T[t][c] = (c<32 ? sin : cos)(t * invf(c&31)) —
// identical expressions to the original epilogue -> consumer bit-identical.
__global__ __launch_bounds__(256) void prep_inputs(
    const float* __restrict__ x, const float* __restrict__ qkv_w,
    const float* __restrict__ out_w, u16* __restrict__ xb,
    u16* __restrict__ wqkvT, u16* __restrict__ woutT,
    float* __restrict__ rtab) {
  __shared__ u16 tile[32][33];
  const int blk = blockIdx.x;
  const int tid = threadIdx.x;
  if (blk < 2048) {
    int i = (blk * 256 + tid) * 8;
#pragma unroll
    for (int j = 0; j < 8; ++j) xb[i + j] = f2b(x[i + j]);
    return;
  }
  if (blk >= 6144) {
    const float LOG1E4 = 9.210340371976184f;
    int base = (blk - 6144) * 4096 + tid * 16;
#pragma unroll
    for (int j = 0; j < 16; ++j) {
      int idx = base + j;
      int t = idx >> 6, c = idx & 63;
      float inv = __expf(-((float)(c & 31)) * (1.0f / 32.0f) * LOG1E4);
      float a = (float)t * inv;
      rtab[idx] = (c < 32) ? fast_sin(a) : fast_cos(a);
    }
    return;
  }
  const float* in; u16* out; int N; int idx;
  if (blk < 5120) { idx = blk - 2048; in = qkv_w; out = wqkvT; N = 3072; }
  else            { idx = blk - 5120; in = out_w; out = woutT; N = 1024; }
  const int nbx = N / 32;
  const int n0 = (idx % nbx) * 32, k0 = (idx / nbx) * 32;
  const int tx = tid & 31, ty = tid >> 5;
  for (int i2 = ty; i2 < 32; i2 += 8)
    tile[i2][tx] = f2b(in[(size_t)(k0 + i2) * N + n0 + tx]);
  __syncthreads();
  for (int i2 = ty; i2 < 32; i2 += 8)
    out[(size_t)(n0 + i2) * 1024 + k0 + tx] = tile[tx][i2];
}

// ======== 64x128 2-phase GEMM (out-projection), f32 out w/ bias =============
// 512 blocks = 2-3/CU; 48KB LDS, (256,3). Same K-order -> bit-identical.
__global__ __launch_bounds__(256, 3) void gemm64_2ph(const u16* __restrict__ A,
                                                     const u16* __restrict__ Bt,
                                                     const float* __restrict__ bias,
                                                     float* __restrict__ C,
                                                     int M, int N, int K) {
  __shared__ alignas(16) u16 As[2][4096];   // [buf][64*64]
  __shared__ alignas(16) u16 Bs[2][8192];   // [buf][128*64]
  const int tid = threadIdx.x;
  const int lane = tid & 63;
  const int wave = tid >> 6;
  const int l15 = lane & 15, quad = lane >> 4;
  const int wm = (wave >> 1) * 32, wn = (wave & 1) * 64;

  const int lin = blockIdx.y * gridDim.x + blockIdx.x;
  const int xcd = lin & 7, loc = lin >> 3;          // loc 0..63
  const int row0 = (xcd * 8 + (loc >> 3)) * 64;     // row-tile 0..63
  const int col0 = (loc & 7) * 128;                 // col-tile 0..7

  const int sr = tid >> 3;
  const size_t soff = (size_t)sr * K + (size_t)((tid & 7) ^ (sr & 7)) * 8;
  const u16* Ab = A + (size_t)row0 * K;
  const u16* Bb = Bt + (size_t)col0 * K;

  const int swz0 = (quad ^ (l15 & 7)) * 8;
  const int swz1 = ((4 + quad) ^ (l15 & 7)) * 8;
  const int arow = (wm + l15) * 64;
  const int brow = (wn + l15) * 64;

  f32x4 acc[2][4] = {};
  const int NTIL = K >> 6;

#define STAGEA(buf, koff)                                                    \
  _Pragma("unroll") for (int p = 0; p < 2; ++p)                              \
      gload_lds16(Ab + (koff) + soff + (size_t)p * 32 * K,                   \
                  &As[buf][(p * 256 + tid) * 8]);
#define STAGEB(buf, koff)                                                    \
  _Pragma("unroll") for (int p = 0; p < 4; ++p)                              \
      gload_lds16(Bb + (koff) + soff + (size_t)p * 32 * K,                   \
                  &Bs[buf][(p * 256 + tid) * 8]);

  STAGEA(0, 0);
  STAGEB(0, 0);
  asm volatile("s_waitcnt vmcnt(0)");
  __builtin_amdgcn_s_barrier();
  asm volatile("" ::: "memory");

  for (int t = 0; t < NTIL; ++t) {
    const int cur = t & 1;
    if (t + 1 < NTIL) {  // uniform branch
      STAGEA(cur ^ 1, (size_t)(t + 1) * 64);
      STAGEB(cur ^ 1, (size_t)(t + 1) * 64);
    }
    bf16x8 af[2][2], bfr[4][2];
#pragma unroll
    for (int i = 0; i < 2; ++i) {
      af[i][0] = *(const bf16x8*)&As[cur][arow + i * 1024 + swz0];
      af[i][1] = *(const bf16x8*)&As[cur][arow + i * 1024 + swz1];
    }
#pragma unroll
    for (int j = 0; j < 4; ++j) {
      bfr[j][0] = *(const bf16x8*)&Bs[cur][brow + j * 1024 + swz0];
      bfr[j][1] = *(const bf16x8*)&Bs[cur][brow + j * 1024 + swz1];
    }
    asm volatile("s_waitcnt lgkmcnt(0)");
    __builtin_amdgcn_sched_barrier(0);
#pragma unroll
    for (int i = 0; i < 2; ++i)
#pragma unroll
      for (int j = 0; j < 4; ++j) {
        acc[i][j] = mfma16(af[i][0], bfr[j][0], acc[i][j]);
        acc[i][j] = mfma16(af[i][1], bfr[j][1], acc[i][j]);
      }
    asm volatile("s_waitcnt vmcnt(0)");
    __builtin_amdgcn_s_barrier();
    asm volatile("" ::: "memory");
  }
#undef STAGEA
#undef STAGEB

#pragma unroll
  for (int j = 0; j < 4; ++j) {
    const int c = col0 + wn + j * 16 + l15;
    const float bv = bias[c];
#pragma unroll
    for (int i = 0; i < 2; ++i) {
      const int rr0 = row0 + wm + i * 16 + quad * 4;
      f32x4 v = acc[i][j];
#pragma unroll
      for (int rr = 0; rr < 4; ++rr)
        C[(size_t)(rr0 + rr) * N + c] = v[rr] + bv;
    }
  }
}

// ==== 128x128 2-phase QKV GEMM + fused RoPE/V-swizzle epilogue ==============
// R11: gemm256_qkv (192 blocks, 25% of CUs idle, 1 lockstep block/CU,
// MfmaUtil 18%) replaced by the session's better-performing 2-phase 128^2
// template: 24x32 = 768 blocks = 2-3/CU, all CUs covered. A 128-col tile
// still covers exactly 2 complete heads of one q/k/v type; the 32KB output
// tile reuses the dead 64KB staging LDS. Epilogue = R10's table-RoPE +
// V k-slot permutation, re-parameterized for 256 threads. K-accumulation
// order identical to gemm256 -> bit-identical numerics.
__device__ __forceinline__ u16* tsw128(u16* base, int row, int col) {
  int byte = row * 256 + ((col * 2) ^ ((row & 15) << 4));
  return (u16*)((char*)base + byte);
}

__global__ __launch_bounds__(256, 2) void gemm_qkv128(
    const u16* __restrict__ A, const u16* __restrict__ Bt,
    const float* __restrict__ bias, u16* __restrict__ qsw,
    u16* __restrict__ ksw, u16* __restrict__ vsw,
    const float* __restrict__ rope_tab, int K) {
  __shared__ alignas(16) u16 lds[32768];  // 64KB: [buf][A|B][128*64] staging
  u16* As0 = &lds[0];
  u16* Bs0 = &lds[8192];
  u16* As1 = &lds[16384];
  u16* Bs1 = &lds[24576];
  const int tid = threadIdx.x;
  const int lane = tid & 63;
  const int wave = tid >> 6;
  const int l15 = lane & 15, quad = lane >> 4;
  const int wm = (wave >> 1) * 64, wn = (wave & 1) * 64;

  // 2D XCD chunking: 768 blocks; XCD x owns 8 row-tiles x 12 col-tiles
  // (2MB A + 3MB B, L2-fit).
  const int lin = blockIdx.y * gridDim.x + blockIdx.x;
  const int xcd = lin & 7, loc = lin >> 3;              // loc 0..95
  const int row0 = ((xcd & 3) * 8 + loc / 12) * 128;    // row-tile 0..31
  const int col0 = ((xcd >> 2) * 12 + loc % 12) * 128;  // col-tile 0..23
  const int NTIL = K >> 6;

  const int sr = tid >> 3;
  const size_t soff = (size_t)sr * K + (size_t)((tid & 7) ^ (sr & 7)) * 8;
  const u16* Ab = A + (size_t)row0 * K;
  const u16* Bb = Bt + (size_t)col0 * K;

  const int swz0 = (quad ^ (l15 & 7)) * 8;
  const int swz1 = ((4 + quad) ^ (l15 & 7)) * 8;
  const int arow = (wm + l15) * 64;
  const int brow = (wn + l15) * 64;

  f32x4 acc[4][4] = {};

#define STAGE8Q(dst, bptr, koff)                                             \
  _Pragma("unroll") for (int p = 0; p < 4; ++p)                              \
      gload_lds16((bptr) + (koff) + soff + (size_t)p * 32 * K,               \
                  &(dst)[(p * 256 + tid) * 8]);

  STAGE8Q(As0, Ab, 0);
  STAGE8Q(Bs0, Bb, 0);
  asm volatile("s_waitcnt vmcnt(0)");
  __builtin_amdgcn_s_barrier();
  asm volatile("" ::: "memory");

  for (int t = 0; t < NTIL; ++t) {
    u16* Ac = (t & 1) ? As1 : As0;
    u16* Bc = (t & 1) ? Bs1 : Bs0;
    if (t + 1 < NTIL) {  // uniform branch
      u16* An = (t & 1) ? As0 : As1;
      u16* Bn = (t & 1) ? Bs0 : Bs1;
      STAGE8Q(An, Ab, (size_t)(t + 1) * 64);
      STAGE8Q(Bn, Bb, (size_t)(t + 1) * 64);
    }
    bf16x8 af[4][2], bfr[4][2];
#pragma unroll
    for (int i = 0; i < 4; ++i) {
      af[i][0]  = *(const bf16x8*)&Ac[arow + i * 1024 + swz0];
      af[i][1]  = *(const bf16x8*)&Ac[arow + i * 1024 + swz1];
      bfr[i][0] = *(const bf16x8*)&Bc[brow + i * 1024 + swz0];
      bfr[i][1] = *(const bf16x8*)&Bc[brow + i * 1024 + swz1];
    }
    asm volatile("s_waitcnt lgkmcnt(0)");
    __builtin_amdgcn_sched_barrier(0);
#pragma unroll
    for (int i = 0; i < 4; ++i)
#pragma unroll
      for (int j = 0; j < 4; ++j) {
        acc[i][j] = mfma16(af[i][0], bfr[j][0], acc[i][j]);
        acc[i][j] = mfma16(af[i][1], bfr[j][1], acc[i][j]);
      }
    asm volatile("s_waitcnt vmcnt(0)");
    __builtin_amdgcn_s_barrier();
    asm volatile("" ::: "memory");
  }
#undef STAGE8Q

  // ---- Fused epilogue phase 1: bf16(acc+bias) -> swizzled 32KB LDS tile ---
  __syncthreads();  // all waves out of the K-loop; staging LDS now dead
#pragma unroll
  for (int j = 0; j < 4; ++j) {
    const int col_in = wn + j * 16 + l15;
    const float bv = bias[col0 + col_in];
#pragma unroll
    for (int i = 0; i < 4; ++i) {
      const int r_in0 = wm + i * 16 + quad * 4;
      f32x4 v = acc[i][j];
#pragma unroll
      for (int rr = 0; rr < 4; ++rr)
        *tsw128(lds, r_in0 + rr, col_in) = f2b(v[rr] + bv);
    }
  }
  __syncthreads();

  // ---- Fused epilogue phase 2: RoPE / V-swizzle from LDS ------------------
  const int tt = col0 >> 10;             // 0=q 1=k 2=v (block-uniform)
  const int h0 = (col0 & 1023) >> 6;     // first of 2 heads in this tile
  const int bb = row0 >> 11;             // batch
  const int tb0 = row0 & 2047;           // first t of this tile

  if (tt < 2) {
    // RoPE for q (scale 0.125) or k (scale 1.0). 128 threads per head.
    u16* dst = (tt == 0) ? qsw : ksw;
    const float scale = (tt == 0) ? 0.125f : 1.0f;
    const int hh = tid >> 7;             // head 0..1 (wave-uniform)
    const int chunk = (tid >> 4) & 7;
    const int tl = tid & 15;
    const int ks = chunk >> 2, qd = chunk & 3;
    const int bh = bb * 16 + h0 + hh;
    const bool low = (ks == 0);          // wave-uniform
    const int cbase = qd * 16;
    const int xbyte0 = (hh * 64 + cbase) * 2;  // 32B-aligned
    const int sw = tl << 4;              // (rrow&15)<<4 == tl<<4
    for (int tb = 0; tb < 4; ++tb) {
      const int tbt = tb0 + tb * 32;     // global t of this 32-row unit
#pragma unroll
      for (int rbloc = 0; rbloc < 2; ++rbloc) {
        const int rrow = tb * 32 + rbloc * 16 + tl;  // row in tile
        const int tg = tbt + rbloc * 16 + tl;        // global t
        const char* rowp = (const char*)lds + rrow * 256;
        bf16x8 q0 = *(const bf16x8*)(rowp + (xbyte0 ^ sw));
        bf16x8 q1 = *(const bf16x8*)(rowp + ((xbyte0 + 16) ^ sw));
        const float* tp = &rope_tab[tg * 64 + cbase];
        float sc[16];
        *(f32x4*)&sc[0]  = *(const f32x4*)(tp);
        *(f32x4*)&sc[4]  = *(const f32x4*)(tp + 4);
        *(f32x4*)&sc[8]  = *(const f32x4*)(tp + 8);
        *(f32x4*)&sc[12] = *(const f32x4*)(tp + 12);
        u16 xs[16];
        *(bf16x8*)&xs[0] = q0;
        *(bf16x8*)&xs[8] = q1;
        union { u16 s[8]; unsigned int u[4]; bf16x8 v; } o;
        float ovv[8];
#pragma unroll
        for (int e = 0; e < 8; ++e) {
          float x1 = b2f(xs[2 * e]), x2 = b2f(xs[2 * e + 1]);
          float sA = sc[2 * e], cA = sc[2 * e + 1];
          float ov = low ? (x1 * cA - x2 * sA) : (x1 * sA + x2 * cA);
          ovv[e] = ov * scale;
        }
#pragma unroll
        for (int p2 = 0; p2 < 4; ++p2)
          o.u[p2] = cvtpk(ovv[2 * p2], ovv[2 * p2 + 1]);
        size_t addr =
            ((((size_t)bh * 128 + (tbt >> 4) + rbloc) * 2 + ks) * 64 +
             qd * 16 + tl) * 8;
        *(bf16x8*)&dst[addr] = o.v;
      }
    }
  } else {
    // V swizzle with k-slot permutation pi(p) = (p>>1) + ((p&1)<<4).
    // 8 units of (head 0..1, 32-row block 0..3), all 256 threads per unit.
    const int ni = tid >> 6, lane2 = tid & 63;
    const int qd = lane2 >> 4, l15b = lane2 & 15;
    for (int unit = 0; unit < 8; ++unit) {
      const int hh = unit >> 2, tb = unit & 3;
      const int bh = bb * 16 + h0 + hh;
      const int tbt = tb0 + tb * 32;
      union { u16 s[8]; bf16x8 v; } o;
#pragma unroll
      for (int e = 0; e < 8; ++e) {
        int p = qd * 8 + e;
        int krow = (p >> 1) + ((p & 1) << 4);
        o.s[e] = *tsw128(lds, tb * 32 + krow, hh * 64 + ni * 16 + l15b);
      }
      *(bf16x8*)&vsw[(((size_t)bh * 64 + (tbt >> 5)) * 4 + ni) * 512 +
                     lane2 * 8] = o.v;
    }
  }
}

// ---------------- Flash attention v9 ----------------------------------------
// R8-stable: kf loads at loop top (short liveness, no spill at VGPR ~116);
// packed u32 P-store + permuted V + cvt_pk + Ll folded into Ps.
__global__ __launch_bounds__(128, 2) void flash_kernel(const u16* __restrict__ qsw,
                                                       const u16* __restrict__ ksw,
                                                       const u16* __restrict__ vsw,
                                                       u16* __restrict__ attn) {
  __shared__ alignas(16) u16 Ps[2 * 5120];  // per-wave [ks32][32 rows][40] 10KB
  // Wave1's region after its loop: Of = 8192B at Ps[5120..9216), Ll = 128B
  // at Ps[9216..9280).
  float* const Of = (float*)&Ps[5120];
  float* const Ll = (float*)&Ps[9216];

  const int tid = threadIdx.x;
  const int w = tid >> 6;
  const int lane = tid & 63;
  const int l15 = lane & 15, quad = lane >> 4;
  const int linear = (int)blockIdx.x;
  const int bh = linear & 31;         // head-major: L2 locality
  const int qt = 63 - (linear >> 5);  // 32-row tile, big first
  const int r0 = qt * 32;
  u16* Psw = &Ps[w * 5120];

  bf16x8 aq[2][2];
#pragma unroll
  for (int mi = 0; mi < 2; ++mi)
#pragma unroll
    for (int ks = 0; ks < 2; ++ks)
      aq[mi][ks] = *(const bf16x8*)&qsw[
          ((((size_t)bh * 128 + qt * 2 + mi) * 2 + ks) * 64 + lane) * 8];

  f32x4 oacc[2][4] = {};
  float lst[8] = {0.f, 0.f, 0.f, 0.f, 0.f, 0.f, 0.f, 0.f};

  const int ktmax = qt >> 2;
  for (int kt = w; kt <= ktmax; kt += 2) {
    // Batched K-fragment loads: 16 independent 1KB reads in flight at once.
    bf16x8 kf[2][8];
#pragma unroll
    for (int ks = 0; ks < 2; ++ks)
#pragma unroll
      for (int ni = 0; ni < 8; ++ni)
        kf[ks][ni] = *(const bf16x8*)&ksw[
            ((((size_t)bh * 128 + kt * 8 + ni) * 2 + ks) * 64 + lane) * 8];

    // S = Q K^T (scale pre-folded into Q)
    f32x4 sacc[2][8] = {};
#pragma unroll
    for (int ks = 0; ks < 2; ++ks)
#pragma unroll
      for (int ni = 0; ni < 8; ++ni) {
        sacc[0][ni] = mfma16(aq[0][ks], kf[ks][ni], sacc[0][ni]);
        sacc[1][ni] = mfma16(aq[1][ks], kf[ks][ni], sacc[1][ni]);
      }

    // Batched V-fragment loads: issued now so their L2 latency is covered by
    // the entire softmax phase below.
    bf16x8 vf[4][4];
#pragma unroll
    for (int ks = 0; ks < 4; ++ks)
#pragma unroll
      for (int ni = 0; ni < 4; ++ni)
        vf[ks][ni] = *(const bf16x8*)&vsw[
            (((size_t)bh * 64 + kt * 4 + ks) * 4 + ni) * 512 + lane * 8];

    const bool diag = (kt == ktmax);
    const int k0 = kt * 128;
#pragma unroll
    for (int mi = 0; mi < 2; ++mi)
#pragma unroll
      for (int r = 0; r < 4; ++r) {
        const int prow = mi * 16 + quad * 4 + r;
        float sv[8];
#pragma unroll
        for (int ni = 0; ni < 8; ++ni) sv[ni] = sacc[mi][ni][r];
        if (diag) {
#pragma unroll
          for (int ni = 0; ni < 8; ++ni)
            if (k0 + ni * 16 + l15 > r0 + prow) sv[ni] = -__builtin_inff();
        }
        float rs = 0.f;
#pragma unroll
        for (int ni = 0; ni < 8; ++ni) {
          float p = __expf(sv[ni]);
          sv[ni] = p;
          rs += p;
        }
        lst[mi * 4 + r] += rsum16(rs);
        // Packed store: cols (c, c+16) -> adjacent slots (2*l15, 2*l15+1).
#pragma unroll
        for (int ni = 0; ni < 8; ni += 2) {
          unsigned int pk = cvtpk(sv[ni], sv[ni + 1]);
          *(unsigned int*)&Psw[(ni >> 1) * 1280 + prow * 40 + 2 * l15] = pk;
        }
      }

    // Wave-private LDS RAW: pin source order (TBAA could hoist the reads).
    asm volatile("" ::: "memory");

#pragma unroll
    for (int ks = 0; ks < 4; ++ks) {
      bf16x8 ap0 = *(const bf16x8*)&Psw[ks * 1280 + l15 * 40 + quad * 8];
      bf16x8 ap1 = *(const bf16x8*)&Psw[ks * 1280 + (16 + l15) * 40 + quad * 8];
#pragma unroll
      for (int ni = 0; ni < 4; ++ni) {
        oacc[0][ni] = mfma16(ap0, vf[ks][ni], oacc[0][ni]);
        oacc[1][ni] = mfma16(ap1, vf[ks][ni], oacc[1][ni]);
      }
    }
  }

  // Static-max merge: partial (O, l) just add. Wave1 publishes via its own
  // (now dead) Ps region; __syncthreads orders the cross-type LDS reuse.
  if (w == 1) {
#pragma unroll
    for (int mi = 0; mi < 2; ++mi)
#pragma unroll
      for (int r = 0; r < 4; ++r) {
        const int row = mi * 16 + quad * 4 + r;
        if (l15 == 0) Ll[row] = lst[mi * 4 + r];
#pragma unroll
        for (int ni = 0; ni < 4; ++ni)
          Of[row * 64 + ni * 16 + l15] = oacc[mi][ni][r];
      }
  }
  __syncthreads();
  if (w == 0) {
    const int b = bh >> 4, h = bh & 15;
#pragma unroll
    for (int mi = 0; mi < 2; ++mi)
#pragma unroll
      for (int r = 0; r < 4; ++r) {
        const int row = mi * 16 + quad * 4 + r;
        const float rl = 1.0f / (lst[mi * 4 + r] + Ll[row]);
        const int trow = r0 + row;
#pragma unroll
        for (int ni = 0; ni < 4; ++ni) {
          float o = oacc[mi][ni][r] + Of[row * 64 + ni * 16 + l15];
          attn[((size_t)b * NT + trow) * ND + h * HD + ni * 16 + l15] = f2b(o * rl);
        }
      }
  }
}

extern "C" void kernel_launch(void* const* d_in, const int* in_sizes, int n_in,
                              void* d_out, int out_size, void* d_ws, size_t ws_size,
                              hipStream_t stream) {
  const float* x = (const float*)d_in[0];      // (B,T,D) f32
  const float* qkv_w = (const float*)d_in[1];  // (D,3D) f32
  const float* qkv_b = (const float*)d_in[2];  // (3D,) f32
  const float* out_w = (const float*)d_in[3];  // (D,D) f32
  const float* out_b = (const float*)d_in[4];  // (D,) f32
  float* out = (float*)d_out;

  u16* ws = (u16*)d_ws;
  u16* xb    = ws;                          // 4096*1024
  u16* wqkvT = xb + (size_t)4096 * 1024;    // 3072*1024
  u16* woutT = wqkvT + 3072 * 1024;         // 1024*1024
  u16* qsw   = woutT + 1024 * 1024;         // 32*2048*64
  u16* ksw   = qsw + (size_t)32 * 2048 * 64;
  u16* vsw   = ksw + (size_t)32 * 2048 * 64;
  u16* attn  = vsw + (size_t)32 * 2048 * 64; // 4096*1024
  float* rtab = (float*)(attn + (size_t)4096 * 1024);  // 2048*64 f32 (512KB)

  // Merged cast + weight transposes + RoPE sin/cos table.
  prep_inputs<<<dim3(6176), 256, 0, stream>>>(
      x, qkv_w, out_w, xb, wqkvT, woutT, rtab);

  // QKV projection: 128^2 2-phase + fused RoPE/V-swizzle epilogue
  // (768 blocks = full CU coverage, 2/CU).
  gemm_qkv128<<<dim3(24, 32), 256, 0, stream>>>(
      xb, wqkvT, qkv_b, qsw, ksw, vsw, rtab, ND);

  flash_kernel<<<dim3(2048), 128, 0, stream>>>(qsw, ksw, vsw, attn);

  // Out-projection: 64x128 2-phase kernel (512 blocks = 2-3/CU).
  gemm64_2ph<<<dim3(ND / 128, NB * NT / 64), 256, 0, stream>>>(
      attn, woutT, out_b, out, NB * NT, ND, ND);
}

// Round 12
// 178.677 us; speedup vs baseline: 1.0158x; 1.0158x over previous
//
#include <hip/hip_runtime.h>

typedef unsigned short u16;
typedef __attribute__((ext_vector_type(8))) __bf16 bf16x8;
typedef __attribute__((ext_vector_type(4))) float f32x4;

#define NB 2
#define NT 2048
#define ND 1024
#define NH 16
#define HD 64

__device__ __forceinline__ float b2f(u16 u) {
  union { float f; unsigned int i; } v; v.i = ((unsigned int)u) << 16; return v.f;
}
__device__ __forceinline__ u16 f2b(float f) {
  union { float f; unsigned int i; } v; v.f = f;
  unsigned int r = (v.i + 0x7FFFu + ((v.i >> 16) & 1u)) >> 16;
  return (u16)r;
}
// 2x f32 -> packed bf16 (RNE, same as f2b) in ONE VALU op. [T12 primitive]
__device__ __forceinline__ unsigned int cvtpk(float lo, float hi) {
  unsigned int pk;
  asm("v_cvt_pk_bf16_f32 %0, %1, %2" : "=v"(pk) : "v"(lo), "v"(hi));
  return pk;
}

__device__ __forceinline__ void gload_lds16(const u16* g, u16* lds) {
  __builtin_amdgcn_global_load_lds(
      (const __attribute__((address_space(1))) unsigned int*)(g),
      (__attribute__((address_space(3))) unsigned int*)(lds),
      16, 0, 0);
}

__device__ __forceinline__ f32x4 mfma16(bf16x8 a, bf16x8 b, f32x4 c) {
  return __builtin_amdgcn_mfma_f32_16x16x32_bf16(a, b, c, 0, 0, 0);
}

// DPP row_ror<N>: 16-lane-domain reduction at VALU latency (no ds_swizzle).
template <int N>
__device__ __forceinline__ float ror16(float x) {
  return __int_as_float(__builtin_amdgcn_update_dpp(
      __float_as_int(x), __float_as_int(x), 0x120 | N, 0xF, 0xF, true));
}
__device__ __forceinline__ float rsum16(float x) {
  x += ror16<8>(x);
  x += ror16<4>(x);
  x += ror16<2>(x);
  x += ror16<1>(x);
  return x;
}

// Fast sin/cos: radians -> revolutions, fract range-reduce, v_sin/v_cos.
__device__ __forceinline__ float fast_sin(float a) {
  float r = a * 0.15915494309189535f;
  r -= floorf(r);
  return __builtin_amdgcn_sinf(r);
}
__device__ __forceinline__ float fast_cos(float a) {
  float r = a * 0.15915494309189535f;
  r -= floorf(r);
  return __builtin_amdgcn_cosf(r);
}

// ---- merged input prep: cast + weight transposes + RoPE sin/cos table ------
// blocks [0,2048): cast; [2048,5120): qkv_w transpose; [5120,6144): out_w;
// [6144,6176): rope table T[t][c] = (c<32 ? sin : cos)(t * invf(c&31)),
// computed with the IDENTICAL expressions the old epilogue used -> the
// consumer stays bit-identical.
__global__ __launch_bounds__(256) void prep_inputs(
    const float* __restrict__ x, const float* __restrict__ qkv_w,
    const float* __restrict__ out_w, u16* __restrict__ xb,
    u16* __restrict__ wqkvT, u16* __restrict__ woutT,
    float* __restrict__ rtab) {
  __shared__ u16 tile[32][33];
  const int blk = blockIdx.x;
  const int tid = threadIdx.x;
  if (blk < 2048) {
    int i = (blk * 256 + tid) * 8;
#pragma unroll
    for (int j = 0; j < 8; ++j) xb[i + j] = f2b(x[i + j]);
    return;
  }
  if (blk >= 6144) {
    const float LOG1E4 = 9.210340371976184f;
    int base = (blk - 6144) * 4096 + tid * 16;
#pragma unroll
    for (int j = 0; j < 16; ++j) {
      int idx = base + j;
      int t = idx >> 6, c = idx & 63;
      float inv = __expf(-((float)(c & 31)) * (1.0f / 32.0f) * LOG1E4);
      float a = (float)t * inv;
      rtab[idx] = (c < 32) ? fast_sin(a) : fast_cos(a);
    }
    return;
  }
  const float* in; u16* out; int N; int idx;
  if (blk < 5120) { idx = blk - 2048; in = qkv_w; out = wqkvT; N = 3072; }
  else            { idx = blk - 5120; in = out_w; out = woutT; N = 1024; }
  const int nbx = N / 32;
  const int n0 = (idx % nbx) * 32, k0 = (idx / nbx) * 32;
  const int tx = tid & 31, ty = tid >> 5;
  for (int i2 = ty; i2 < 32; i2 += 8)
    tile[i2][tx] = f2b(in[(size_t)(k0 + i2) * N + n0 + tx]);
  __syncthreads();
  for (int i2 = ty; i2 < 32; i2 += 8)
    out[(size_t)(n0 + i2) * 1024 + k0 + tx] = tile[tx][i2];
}

// ======== 64x128 2-phase GEMM (out-projection), f32 out w/ bias =============
// 512 blocks = 2-3/CU; 48KB LDS, (256,3). Same K-order -> bit-identical.
__global__ __launch_bounds__(256, 3) void gemm64_2ph(const u16* __restrict__ A,
                                                     const u16* __restrict__ Bt,
                                                     const float* __restrict__ bias,
                                                     float* __restrict__ C,
                                                     int M, int N, int K) {
  __shared__ alignas(16) u16 As[2][4096];   // [buf][64*64]
  __shared__ alignas(16) u16 Bs[2][8192];   // [buf][128*64]
  const int tid = threadIdx.x;
  const int lane = tid & 63;
  const int wave = tid >> 6;
  const int l15 = lane & 15, quad = lane >> 4;
  const int wm = (wave >> 1) * 32, wn = (wave & 1) * 64;

  const int lin = blockIdx.y * gridDim.x + blockIdx.x;
  const int xcd = lin & 7, loc = lin >> 3;          // loc 0..63
  const int row0 = (xcd * 8 + (loc >> 3)) * 64;     // row-tile 0..63
  const int col0 = (loc & 7) * 128;                 // col-tile 0..7

  const int sr = tid >> 3;
  const size_t soff = (size_t)sr * K + (size_t)((tid & 7) ^ (sr & 7)) * 8;
  const u16* Ab = A + (size_t)row0 * K;
  const u16* Bb = Bt + (size_t)col0 * K;

  const int swz0 = (quad ^ (l15 & 7)) * 8;
  const int swz1 = ((4 + quad) ^ (l15 & 7)) * 8;
  const int arow = (wm + l15) * 64;
  const int brow = (wn + l15) * 64;

  f32x4 acc[2][4] = {};
  const int NTIL = K >> 6;

#define STAGEA(buf, koff)                                                    \
  _Pragma("unroll") for (int p = 0; p < 2; ++p)                              \
      gload_lds16(Ab + (koff) + soff + (size_t)p * 32 * K,                   \
                  &As[buf][(p * 256 + tid) * 8]);
#define STAGEB(buf, koff)                                                    \
  _Pragma("unroll") for (int p = 0; p < 4; ++p)                              \
      gload_lds16(Bb + (koff) + soff + (size_t)p * 32 * K,                   \
                  &Bs[buf][(p * 256 + tid) * 8]);

  STAGEA(0, 0);
  STAGEB(0, 0);
  asm volatile("s_waitcnt vmcnt(0)");
  __builtin_amdgcn_s_barrier();
  asm volatile("" ::: "memory");

  for (int t = 0; t < NTIL; ++t) {
    const int cur = t & 1;
    if (t + 1 < NTIL) {  // uniform branch
      STAGEA(cur ^ 1, (size_t)(t + 1) * 64);
      STAGEB(cur ^ 1, (size_t)(t + 1) * 64);
    }
    bf16x8 af[2][2], bfr[4][2];
#pragma unroll
    for (int i = 0; i < 2; ++i) {
      af[i][0] = *(const bf16x8*)&As[cur][arow + i * 1024 + swz0];
      af[i][1] = *(const bf16x8*)&As[cur][arow + i * 1024 + swz1];
    }
#pragma unroll
    for (int j = 0; j < 4; ++j) {
      bfr[j][0] = *(const bf16x8*)&Bs[cur][brow + j * 1024 + swz0];
      bfr[j][1] = *(const bf16x8*)&Bs[cur][brow + j * 1024 + swz1];
    }
    asm volatile("s_waitcnt lgkmcnt(0)");
    __builtin_amdgcn_sched_barrier(0);
#pragma unroll
    for (int i = 0; i < 2; ++i)
#pragma unroll
      for (int j = 0; j < 4; ++j) {
        acc[i][j] = mfma16(af[i][0], bfr[j][0], acc[i][j]);
        acc[i][j] = mfma16(af[i][1], bfr[j][1], acc[i][j]);
      }
    asm volatile("s_waitcnt vmcnt(0)");
    __builtin_amdgcn_s_barrier();
    asm volatile("" ::: "memory");
  }
#undef STAGEA
#undef STAGEB

#pragma unroll
  for (int j = 0; j < 4; ++j) {
    const int c = col0 + wn + j * 16 + l15;
    const float bv = bias[c];
#pragma unroll
    for (int i = 0; i < 2; ++i) {
      const int rr0 = row0 + wm + i * 16 + quad * 4;
      f32x4 v = acc[i][j];
#pragma unroll
      for (int rr = 0; rr < 4; ++rr)
        C[(size_t)(rr0 + rr) * N + c] = v[rr] + bv;
    }
  }
}

// ============ 256x256 8-phase GEMM + FUSED RoPE/V-swizzle epilogue ==========
// R10-stable (session best, 179.3us): sin/cos from the precomputed table
// (bit-identical values) and x-operands via 2x ds_read_b128 per iteration
// (XOR swizzle maps each 16B unit contiguously).
__device__ __forceinline__ void stage2(const u16* g0, const u16* g1, u16* l,
                                       int tid) {
  gload_lds16(g0, &l[tid * 8]);
  gload_lds16(g1, &l[(512 + tid) * 8]);
}

// Swizzled u16 pointer into the 256x256 bf16 LDS tile (row-major 512B rows).
__device__ __forceinline__ u16* tsw(u16* base, int row, int col) {
  int byte = row * 512 + ((col * 2) ^ ((row & 15) << 4));
  return (u16*)((char*)base + byte);
}

#define AH(b, h) (&lds[((b) * 2 + (h)) * 8192])
#define BH(b, h) (&lds[32768 + ((b) * 2 + (h)) * 8192])

#define LOAD_AFX(dst, base)                                                 \
  _Pragma("unroll") for (int mm = 0; mm < 4; ++mm) {                        \
    dst[mm][0] = *(const bf16x8*)&(base)[arow + mm * 2048 + swz0];          \
    dst[mm][1] = *(const bf16x8*)&(base)[arow + mm * 2048 + swz1];          \
  }
#define LOAD_BF(base)                                                       \
  _Pragma("unroll") for (int nn = 0; nn < 2; ++nn) {                        \
    bfr[nn][0] = *(const bf16x8*)&(base)[brow + nn * 4096 + swz0];          \
    bfr[nn][1] = *(const bf16x8*)&(base)[brow + nn * 4096 + swz1];          \
  }
#define MFMA_QX(afv, MA, NQ)                                                \
  _Pragma("unroll") for (int mm = 0; mm < 4; ++mm)                          \
  _Pragma("unroll") for (int nn = 0; nn < 2; ++nn) {                        \
    acc[(MA) * 4 + mm][(NQ) * 2 + nn] =                                     \
        mfma16(afv[mm][0], bfr[nn][0], acc[(MA) * 4 + mm][(NQ) * 2 + nn]);  \
    acc[(MA) * 4 + mm][(NQ) * 2 + nn] =                                     \
        mfma16(afv[mm][1], bfr[nn][1], acc[(MA) * 4 + mm][(NQ) * 2 + nn]);  \
  }
#define PH_SYNC                                                             \
  __builtin_amdgcn_s_barrier();                                             \
  asm volatile("s_waitcnt lgkmcnt(0)");                                     \
  __builtin_amdgcn_sched_barrier(0);                                        \
  __builtin_amdgcn_s_setprio(1);
#define PH_END                                                              \
  __builtin_amdgcn_s_setprio(0);                                            \
  __builtin_amdgcn_s_barrier();                                             \
  asm volatile("" ::: "memory");

__global__ __launch_bounds__(512, 2) void gemm256_qkv(const u16* __restrict__ A,
                                                      const u16* __restrict__ Bt,
                                                      const float* __restrict__ bias,
                                                      u16* __restrict__ qsw,
                                                      u16* __restrict__ ksw,
                                                      u16* __restrict__ vsw,
                                                      const float* __restrict__ rope_tab,
                                                      int K) {
  __shared__ alignas(16) u16 lds[65536];  // 128 KiB
  const int tid = threadIdx.x;
  const int lane = tid & 63;
  const int wave = tid >> 6;
  const int l15 = lane & 15, quad = lane >> 4;
  const int wm = wave >> 2, wn = wave & 3;

  // 2D XCD chunking (grid fixed at 12x16 for QKV).
  const int lin = blockIdx.y * gridDim.x + blockIdx.x;
  const int xcd = lin & 7, loc = lin >> 3;              // loc 0..23
  const int row0 = ((xcd & 3) * 4 + loc / 6) * 256;     // tile_row 0..15
  const int col0 = ((xcd >> 2) * 6 + loc % 6) * 256;    // tile_col 0..11
  const int NTIL = K >> 6;

  // Per-thread staging offset; second chunk is row+64 (same chunk-xor since
  // (r+64)&7 == r&7), i.e. exactly +64*K elements. A/B halves at +128*K.
  const int sr = tid >> 3;
  const size_t soff = (size_t)sr * K + (size_t)((tid & 7) ^ (sr & 7)) * 8;
  const size_t hK = (size_t)64 * K;
  const u16* A0p = A + (size_t)row0 * K + soff;
  const u16* A1p = A0p + 2 * hK;
  const u16* B0p = Bt + (size_t)col0 * K + soff;
  const u16* B1p = B0p + 2 * hK;

  // ds_read offsets: row r = <frag-base> + l15 (r&7 == l15&7), chunk^=(r&7).
  const int swz0 = (quad ^ (l15 & 7)) * 8;
  const int swz1 = ((4 + quad) ^ (l15 & 7)) * 8;
  const int arow = (wm * 16 + l15) * 64;
  const int brow = (wn * 16 + l15) * 64;

  f32x4 acc[8][4] = {};

  // Prologue: steady-state issue order so vmcnt(4) => tile0 fully landed.
  stage2(B0p, B0p + hK, BH(0, 0), tid);
  stage2(A1p, A1p + hK, AH(0, 1), tid);
  stage2(A0p, A0p + hK, AH(0, 0), tid);
  stage2(B1p, B1p + hK, BH(0, 1), tid);
  {
    int tp = (NTIL > 1) ? 1 : 0;
    stage2(B0p + tp * 64, B0p + tp * 64 + hK, BH(1, 0), tid);
    stage2(A1p + tp * 64, A1p + tp * 64 + hK, AH(1, 1), tid);
  }
  asm volatile("s_waitcnt vmcnt(4)");
  __builtin_amdgcn_s_barrier();
  asm volatile("" ::: "memory");

  bf16x8 afA[4][2], afB[4][2], bfr[2][2];
#pragma unroll 2
  for (int t = 0; t < NTIL; ++t) {
    const int cur = t & 1, nxt = cur ^ 1;
    const int o1 = ((t + 1 < NTIL) ? t + 1 : NTIL - 1) * 64;
    const int o2 = ((t + 2 < NTIL) ? t + 2 : NTIL - 1) * 64;
    u16* Ac0 = AH(cur, 0);
    u16* Ac1 = AH(cur, 1);
    u16* Bc0 = BH(cur, 0);
    u16* Bc1 = BH(cur, 1);

    // P1 (MA0,NB0): load afA + B0. A0(t+1) -> nxt slot (dead since t-1 end).
    LOAD_AFX(afA, Ac0);
    LOAD_BF(Bc0);
    stage2(A0p + o1, A0p + o1 + hK, AH(nxt, 0), tid);
    PH_SYNC; MFMA_QX(afA, 0, 0); PH_END;

    // P2 (MA1,NB0): load afB; bfr reused. B1(t+1) -> nxt slot.
    LOAD_AFX(afB, Ac1);
    stage2(B1p + o1, B1p + o1 + hK, BH(nxt, 1), tid);
    PH_SYNC; MFMA_QX(afB, 1, 0); PH_END;

    // P3 (MA1,NB1): load B1 into bfr (B0 dead after P2); afB reused.
    // B0(t+2) -> cur slot (all waves' reads of it finished at P1).
    LOAD_BF(Bc1);
    stage2(B0p + o2, B0p + o2 + hK, Bc0, tid);
    PH_SYNC; MFMA_QX(afB, 1, 1); PH_END;

    // P4 (MA0,NB1): pure-MFMA phase — afA and bfr both resident, 0 ds_reads.
    // A1(t+2) -> cur slot (dead since P2).
    stage2(A1p + o2, A1p + o2 + hK, Ac1, tid);
    __builtin_amdgcn_s_barrier();
    __builtin_amdgcn_sched_barrier(0);
    __builtin_amdgcn_s_setprio(1);
    MFMA_QX(afA, 0, 1);
    __builtin_amdgcn_s_setprio(0);
    // Counted wait, once per K-tile: tile t+1 (4 oldest halves) landed; the
    // 2 youngest halves (tile t+2) stay in flight across the barrier.
    asm volatile("s_waitcnt vmcnt(4)");
    __builtin_amdgcn_s_barrier();
    asm volatile("" ::: "memory");
  }
  asm volatile("s_waitcnt vmcnt(0)");  // all tail clamp stages issued by US
  __syncthreads();                     // ...and by every other wave: landed

  // ---- Fused epilogue phase 1: bf16(acc+bias) -> swizzled LDS tile --------
#pragma unroll
  for (int ni = 0; ni < 4; ++ni) {
    const int col_in = (ni >> 1) * 128 + (ni & 1) * 64 + wn * 16 + l15;
    const float bv = bias[col0 + col_in];
#pragma unroll
    for (int mi = 0; mi < 8; ++mi) {
      const int r_in0 = (mi >> 2) * 128 + (mi & 3) * 32 + wm * 16 + quad * 4;
      f32x4 v = acc[mi][ni];
#pragma unroll
      for (int rr = 0; rr < 4; ++rr)
        *tsw(lds, r_in0 + rr, col_in) = f2b(v[rr] + bv);
    }
  }
  __syncthreads();

  // ---- Fused epilogue phase 2: RoPE / V-swizzle from LDS ------------------
  const int tt = col0 >> 10;             // 0=q 1=k 2=v (block-uniform)
  const int h0 = (col0 & 1023) >> 6;     // first of 4 heads in this tile
  const int bb = row0 >> 11;             // batch
  const int tb0 = row0 & 2047;           // first t of this tile

  if (tt < 2) {
    // RoPE for q (scale 0.125) or k (scale 1.0). 128 threads per head.
    u16* dst = (tt == 0) ? qsw : ksw;
    const float scale = (tt == 0) ? 0.125f : 1.0f;
    const int hh = tid >> 7;             // head 0..3 (wave-uniform)
    const int chunk = (tid >> 4) & 7;
    const int tl = tid & 15;
    const int ks = chunk >> 2, qd = chunk & 3;
    const int bh = bb * 16 + h0 + hh;
    const bool low = (ks == 0);          // cc<32 <=> ks==0 (wave-uniform)
    const int cbase = qd * 16;           // c1a = cbase + 2e
    const int xbyte0 = (hh * 64 + cbase) * 2;  // 32B-aligned LDS byte base
    const int sw = tl << 4;              // (rrow&15)<<4 == tl<<4
    for (int tb = 0; tb < 8; ++tb) {
      const int tbt = tb0 + tb * 32;     // global t of this 32-row unit
#pragma unroll
      for (int rbloc = 0; rbloc < 2; ++rbloc) {
        const int rrow = tb * 32 + rbloc * 16 + tl;  // row in tile
        const int tg = tbt + rbloc * 16 + tl;        // global t
        const char* rowp = (const char*)lds + rrow * 512;
        bf16x8 q0 = *(const bf16x8*)(rowp + (xbyte0 ^ sw));
        bf16x8 q1 = *(const bf16x8*)(rowp + ((xbyte0 + 16) ^ sw));
        const float* tp = &rope_tab[tg * 64 + cbase];
        float sc[16];
        *(f32x4*)&sc[0]  = *(const f32x4*)(tp);
        *(f32x4*)&sc[4]  = *(const f32x4*)(tp + 4);
        *(f32x4*)&sc[8]  = *(const f32x4*)(tp + 8);
        *(f32x4*)&sc[12] = *(const f32x4*)(tp + 12);
        u16 xs[16];
        *(bf16x8*)&xs[0] = q0;
        *(bf16x8*)&xs[8] = q1;
        union { u16 s[8]; unsigned int u[4]; bf16x8 v; } o;
        float ovv[8];
#pragma unroll
        for (int e = 0; e < 8; ++e) {
          float x1 = b2f(xs[2 * e]), x2 = b2f(xs[2 * e + 1]);
          float sA = sc[2 * e], cA = sc[2 * e + 1];
          float ov = low ? (x1 * cA - x2 * sA) : (x1 * sA + x2 * cA);
          ovv[e] = ov * scale;
        }
#pragma unroll
        for (int p2 = 0; p2 < 4; ++p2)
          o.u[p2] = cvtpk(ovv[2 * p2], ovv[2 * p2 + 1]);
        size_t addr =
            ((((size_t)bh * 128 + (tbt >> 4) + rbloc) * 2 + ks) * 64 +
             qd * 16 + tl) * 8;
        *(bf16x8*)&dst[addr] = o.v;
      }
    }
  } else {
    // V swizzle with k-slot permutation pi(p) = (p>>1) + ((p&1)<<4).
    // 32 units of (head, 32-row block); 2 units in flight (512 thr / 256).
    const int u = tid >> 8;              // 0..1
    const int utid = tid & 255;
    const int ni = utid >> 6, lane2 = utid & 63;
    const int qd = lane2 >> 4, l15b = lane2 & 15;
    for (int it = 0; it < 16; ++it) {
      const int unit = it * 2 + u;       // 0..31
      const int hh = unit >> 3, tb = unit & 7;
      const int bh = bb * 16 + h0 + hh;
      const int tbt = tb0 + tb * 32;
      union { u16 s[8]; bf16x8 v; } o;
#pragma unroll
      for (int e = 0; e < 8; ++e) {
        int p = qd * 8 + e;
        int krow = (p >> 1) + ((p & 1) << 4);
        o.s[e] = *tsw(lds, tb * 32 + krow, hh * 64 + ni * 16 + l15b);
      }
      *(bf16x8*)&vsw[(((size_t)bh * 64 + (tbt >> 5)) * 4 + ni) * 512 +
                     lane2 * 8] = o.v;
    }
  }
}

// ---------------- Flash attention v9 ----------------------------------------
// R8-stable: kf loads at loop top (short liveness, no spill at VGPR ~116);
// packed u32 P-store + permuted V + cvt_pk + Ll folded into Ps.
__global__ __launch_bounds__(128, 2) void flash_kernel(const u16* __restrict__ qsw,
                                                       const u16* __restrict__ ksw,
                                                       const u16* __restrict__ vsw,
                                                       u16* __restrict__ attn) {
  __shared__ alignas(16) u16 Ps[2 * 5120];  // per-wave [ks32][32 rows][40] 10KB
  // Wave1's region after its loop: Of = 8192B at Ps[5120..9216), Ll = 128B
  // at Ps[9216..9280).
  float* const Of = (float*)&Ps[5120];
  float* const Ll = (float*)&Ps[9216];

  const int tid = threadIdx.x;
  const int w = tid >> 6;
  const int lane = tid & 63;
  const int l15 = lane & 15, quad = lane >> 4;
  const int linear = (int)blockIdx.x;
  const int bh = linear & 31;         // head-major: L2 locality
  const int qt = 63 - (linear >> 5);  // 32-row tile, big first
  const int r0 = qt * 32;
  u16* Psw = &Ps[w * 5120];

  bf16x8 aq[2][2];
#pragma unroll
  for (int mi = 0; mi < 2; ++mi)
#pragma unroll
    for (int ks = 0; ks < 2; ++ks)
      aq[mi][ks] = *(const bf16x8*)&qsw[
          ((((size_t)bh * 128 + qt * 2 + mi) * 2 + ks) * 64 + lane) * 8];

  f32x4 oacc[2][4] = {};
  float lst[8] = {0.f, 0.f, 0.f, 0.f, 0.f, 0.f, 0.f, 0.f};

  const int ktmax = qt >> 2;
  for (int kt = w; kt <= ktmax; kt += 2) {
    // Batched K-fragment loads: 16 independent 1KB reads in flight at once.
    bf16x8 kf[2][8];
#pragma unroll
    for (int ks = 0; ks < 2; ++ks)
#pragma unroll
      for (int ni = 0; ni < 8; ++ni)
        kf[ks][ni] = *(const bf16x8*)&ksw[
            ((((size_t)bh * 128 + kt * 8 + ni) * 2 + ks) * 64 + lane) * 8];

    // S = Q K^T (scale pre-folded into Q)
    f32x4 sacc[2][8] = {};
#pragma unroll
    for (int ks = 0; ks < 2; ++ks)
#pragma unroll
      for (int ni = 0; ni < 8; ++ni) {
        sacc[0][ni] = mfma16(aq[0][ks], kf[ks][ni], sacc[0][ni]);
        sacc[1][ni] = mfma16(aq[1][ks], kf[ks][ni], sacc[1][ni]);
      }

    // Batched V-fragment loads: issued now so their L2 latency is covered by
    // the entire softmax phase below.
    bf16x8 vf[4][4];
#pragma unroll
    for (int ks = 0; ks < 4; ++ks)
#pragma unroll
      for (int ni = 0; ni < 4; ++ni)
        vf[ks][ni] = *(const bf16x8*)&vsw[
            (((size_t)bh * 64 + kt * 4 + ks) * 4 + ni) * 512 + lane * 8];

    const bool diag = (kt == ktmax);
    const int k0 = kt * 128;
#pragma unroll
    for (int mi = 0; mi < 2; ++mi)
#pragma unroll
      for (int r = 0; r < 4; ++r) {
        const int prow = mi * 16 + quad * 4 + r;
        float sv[8];
#pragma unroll
        for (int ni = 0; ni < 8; ++ni) sv[ni] = sacc[mi][ni][r];
        if (diag) {
#pragma unroll
          for (int ni = 0; ni < 8; ++ni)
            if (k0 + ni * 16 + l15 > r0 + prow) sv[ni] = -__builtin_inff();
        }
        float rs = 0.f;
#pragma unroll
        for (int ni = 0; ni < 8; ++ni) {
          float p = __expf(sv[ni]);
          sv[ni] = p;
          rs += p;
        }
        lst[mi * 4 + r] += rsum16(rs);
        // Packed store: cols (c, c+16) -> adjacent slots (2*l15, 2*l15+1).
#pragma unroll
        for (int ni = 0; ni < 8; ni += 2) {
          unsigned int pk = cvtpk(sv[ni], sv[ni + 1]);
          *(unsigned int*)&Psw[(ni >> 1) * 1280 + prow * 40 + 2 * l15] = pk;
        }
      }

    // Wave-private LDS RAW: pin source order (TBAA could hoist the reads).
    asm volatile("" ::: "memory");

#pragma unroll
    for (int ks = 0; ks < 4; ++ks) {
      bf16x8 ap0 = *(const bf16x8*)&Psw[ks * 1280 + l15 * 40 + quad * 8];
      bf16x8 ap1 = *(const bf16x8*)&Psw[ks * 1280 + (16 + l15) * 40 + quad * 8];
#pragma unroll
      for (int ni = 0; ni < 4; ++ni) {
        oacc[0][ni] = mfma16(ap0, vf[ks][ni], oacc[0][ni]);
        oacc[1][ni] = mfma16(ap1, vf[ks][ni], oacc[1][ni]);
      }
    }
  }

  // Static-max merge: partial (O, l) just add. Wave1 publishes via its own
  // (now dead) Ps region; __syncthreads orders the cross-type LDS reuse.
  if (w == 1) {
#pragma unroll
    for (int mi = 0; mi < 2; ++mi)
#pragma unroll
      for (int r = 0; r < 4; ++r) {
        const int row = mi * 16 + quad * 4 + r;
        if (l15 == 0) Ll[row] = lst[mi * 4 + r];
#pragma unroll
        for (int ni = 0; ni < 4; ++ni)
          Of[row * 64 + ni * 16 + l15] = oacc[mi][ni][r];
      }
  }
  __syncthreads();
  if (w == 0) {
    const int b = bh >> 4, h = bh & 15;
#pragma unroll
    for (int mi = 0; mi < 2; ++mi)
#pragma unroll
      for (int r = 0; r < 4; ++r) {
        const int row = mi * 16 + quad * 4 + r;
        const float rl = 1.0f / (lst[mi * 4 + r] + Ll[row]);
        const int trow = r0 + row;
#pragma unroll
        for (int ni = 0; ni < 4; ++ni) {
          float o = oacc[mi][ni][r] + Of[row * 64 + ni * 16 + l15];
          attn[((size_t)b * NT + trow) * ND + h * HD + ni * 16 + l15] = f2b(o * rl);
        }
      }
  }
}

extern "C" void kernel_launch(void* const* d_in, const int* in_sizes, int n_in,
                              void* d_out, int out_size, void* d_ws, size_t ws_size,
                              hipStream_t stream) {
  const float* x = (const float*)d_in[0];      // (B,T,D) f32
  const float* qkv_w = (const float*)d_in[1];  // (D,3D) f32
  const float* qkv_b = (const float*)d_in[2];  // (3D,) f32
  const float* out_w = (const float*)d_in[3];  // (D,D) f32
  const float* out_b = (const float*)d_in[4];  // (D,) f32
  float* out = (float*)d_out;

  u16* ws = (u16*)d_ws;
  u16* xb    = ws;                          // 4096*1024
  u16* wqkvT = xb + (size_t)4096 * 1024;    // 3072*1024
  u16* woutT = wqkvT + 3072 * 1024;         // 1024*1024
  u16* qsw   = woutT + 1024 * 1024;         // 32*2048*64
  u16* ksw   = qsw + (size_t)32 * 2048 * 64;
  u16* vsw   = ksw + (size_t)32 * 2048 * 64;
  u16* attn  = vsw + (size_t)32 * 2048 * 64; // 4096*1024
  float* rtab = (float*)(attn + (size_t)4096 * 1024);  // 2048*64 f32 (512KB)

  // Merged cast + weight transposes + RoPE sin/cos table.
  prep_inputs<<<dim3(6176), 256, 0, stream>>>(
      x, qkv_w, out_w, xb, wqkvT, woutT, rtab);

  // QKV projection + fused RoPE/V-swizzle epilogue (table-driven trig).
  gemm256_qkv<<<dim3(12, 16), 512, 0, stream>>>(
      xb, wqkvT, qkv_b, qsw, ksw, vsw, rtab, ND);

  flash_kernel<<<dim3(2048), 128, 0, stream>>>(qsw, ksw, vsw, attn);

  // Out-projection: 64x128 2-phase kernel (512 blocks = 2-3/CU).
  gemm64_2ph<<<dim3(ND / 128, NB * NT / 64), 256, 0, stream>>>(
      attn, woutT, out_b, out, NB * NT, ND, ND);
}